// Round 5
// baseline (6826.607 us; speedup 1.0000x reference)
//
#include <hip/hip_runtime.h>
#include <hip/hip_bf16.h>
#include <cstdint>

typedef __bf16 bf16x8 __attribute__((ext_vector_type(8)));
typedef float  f32x4  __attribute__((ext_vector_type(4)));
typedef __hip_bfloat16 bf16;

__device__ __forceinline__ float sigmoidf_(float x) { return 1.0f / (1.0f + __expf(-x)); }

// Problem: B=256, T=128, D=64, H=512, 4H=2048. Output (256,255,64) f32.
// Packed weight layout: np = j*4 + g  <->  n = g*512 + j   (gates interleaved per
// output column so a 32-pcol slice = 8 output cols x 4 gates, self-contained).
// ws layout (byte offsets, 16-aligned)
#define OFF_U0      0u           // Ufold0 packed: 2048 x 512 bf16 (2 MB)
#define OFF_U1      2097152u     // Ufold1 packed (2 MB)
#define OFF_WE0PK   4194304u     // We0 packed: 2048 x 64 bf16 (256 KB)
#define OFF_WE1PK   4456448u     // We1 packed: 2048 x 512 bf16 (2 MB)
#define OFF_WDPK    6553600u     // Wdense^T: 64 x 512 bf16 (64 KB)
#define OFF_BE0P    6619136u     // be0 permuted f32 (8 KB)
#define OFF_BE1P    6627328u
#define OFF_B0F     6635520u     // folded dec bias 0 (8 KB)
#define OFF_B1F     6643712u
#define OFF_A0      6651904u     // enc last-step input bf16: 256 x 64 (32 KB)
#define OFF_H1      6684672u     // enc layer1 h bf16: 256 x 512 (256 KB)
#define OFF_BAR     6946816u     // barrier flags: 4 groups x 64 u32 (1 KB)
#define OFF_HALL    7471104u     // h history bf16: 255 x 256 x 512 (66.8 MB)
#define BH          131072       // elems per h slab (256*512)

// ---- one-time prep kernels ----------------------------------------------

__global__ void cast_x(const float* __restrict__ enc, bf16* __restrict__ A0) {
    int i = blockIdx.x * 256 + threadIdx.x;           // 16384 total
    int b = i >> 6, d = i & 63;
    A0[i] = __float2bfloat16(enc[(b * 128 + 127) * 64 + d]);
}

// out[np][k] = W[k][n],  np = j*4+g, n = g*512+j
__global__ void pack_gatew(const float* __restrict__ W, bf16* __restrict__ out, int K) {
    int np = blockIdx.x;
    int j = np >> 2, g = np & 3;
    int n = g * 512 + j;
    for (int k = threadIdx.x; k < K; k += blockDim.x)
        out[np * K + k] = __float2bfloat16(W[k * 2048 + n]);
}

__global__ void pack_wd(const float* __restrict__ Wdense, bf16* __restrict__ out) {
    int d = blockIdx.x;                               // 64
    for (int k = threadIdx.x; k < 512; k += 256)
        out[d * 512 + k] = __float2bfloat16(Wdense[k * 64 + d]);
}

// Ufold[np][hk] = sum_d Wdense[hk][d]*Wd[d][n] + Ud[hk][n]
__global__ void fold_u(const float* __restrict__ Wdense, const float* __restrict__ Wd,
                       const float* __restrict__ Ud, bf16* __restrict__ out) {
    __shared__ float wcol[64];
    int np = blockIdx.x;
    int j = np >> 2, g = np & 3;
    int n = g * 512 + j;
    if (threadIdx.x < 64) wcol[threadIdx.x] = Wd[threadIdx.x * 2048 + n];
    __syncthreads();
    for (int hk = threadIdx.x; hk < 512; hk += 256) {
        float s = Ud[hk * 2048 + n];
        const float* wr = Wdense + hk * 64;
        #pragma unroll
        for (int d = 0; d < 64; ++d) s += wr[d] * wcol[d];
        out[np * 512 + hk] = __float2bfloat16(s);
    }
}

__global__ void prep_bias(const float* __restrict__ be0, const float* __restrict__ be1,
                          const float* __restrict__ bd0, const float* __restrict__ bd1,
                          const float* __restrict__ bdense,
                          const float* __restrict__ Wd0, const float* __restrict__ Wd1,
                          float* __restrict__ be0p, float* __restrict__ be1p,
                          float* __restrict__ b0f, float* __restrict__ b1f) {
    int np = blockIdx.x * blockDim.x + threadIdx.x;
    if (np >= 2048) return;
    int j = np >> 2, g = np & 3;
    int n = g * 512 + j;
    be0p[np] = be0[n];
    be1p[np] = be1[n];
    float s0 = bd0[n], s1 = bd1[n];
    for (int d = 0; d < 64; ++d) {
        float bv = bdense[d];
        s0 += bv * Wd0[d * 2048 + n];
        s1 += bv * Wd1[d * 2048 + n];
    }
    b0f[np] = s0;
    b1f[np] = s1;
}

// ---- persistent-kernel device helpers ------------------------------------

// Stage rows x RB bytes from global (row-major, contiguous) into LDS with
// T2 XOR swizzle: dst_byte = off ^ ((row&7)<<4). rbLog >= 7.
__device__ __forceinline__ void stage_lds(const char* __restrict__ g, char* lds,
                                          int nbytes, int rbLog, int tid) {
    for (int off = tid * 16; off < nbytes; off += 256 * 16) {
        uint4 v = *(const uint4*)(g + off);
        int row = off >> rbLog;
        *(uint4*)(lds + (off ^ ((row & 7) << 4))) = v;
    }
}

// Wave-tile 16 rows x 32 pcols, K=KDIM. A rows = w*16.., B rows = pcol 0..31.
template <int KDIM>
__device__ __forceinline__ void mfma_cell(const char* at, const char* ut,
                                          int w, int lane, f32x4 acc[2]) {
    const int lr = lane & 15, kq = lane >> 4;
    constexpr int RB = KDIM * 2;
    acc[0] = f32x4{0.f, 0.f, 0.f, 0.f};
    acc[1] = f32x4{0.f, 0.f, 0.f, 0.f};
    #pragma unroll
    for (int kk = 0; kk < KDIM / 32; ++kk) {
        int colb = kk * 64 + kq * 16;
        int arow = w * 16 + lr;
        bf16x8 a = *(const bf16x8*)(at + arow * RB + (colb ^ ((arow & 7) << 4)));
        #pragma unroll
        for (int n = 0; n < 2; ++n) {
            int brow = n * 16 + lr;
            bf16x8 b = *(const bf16x8*)(ut + brow * RB + (colb ^ ((brow & 7) << 4)));
            acc[n] = __builtin_amdgcn_mfma_f32_16x16x32_bf16(a, b, acc[n], 0, 0, 0);
        }
    }
}

// D layout: col = lane&15, row = (lane>>4)*4 + r  [verified m89/m91, r4-passing]
__device__ __forceinline__ void write_z(float* zf, int w, int lane, const f32x4 acc[2]) {
    #pragma unroll
    for (int n = 0; n < 2; ++n)
        #pragma unroll
        for (int r = 0; r < 4; ++r)
            zf[(w * 16 + (lane >> 4) * 4 + r) * 36 + n * 16 + (lane & 15)] = acc[n][r];
}

// MODE: 0 = enc no-c, 1 = enc init-c, 2 = dec (uses+updates c)
template <int MODE>
__device__ __forceinline__ void gates_store(const float* zf, const float* __restrict__ bias,
                                            int rb, int cs, int tid, float c[2],
                                            bf16* __restrict__ hout) {
    #pragma unroll
    for (int p = 0; p < 2; ++p) {
        int pr = p * 256 + tid;
        int r = pr >> 3, jl = pr & 7;
        f32x4 zv = *(const f32x4*)(zf + r * 36 + jl * 4);
        f32x4 bv = *(const f32x4*)(bias + (cs * 8 + jl) * 4);
        float zi = zv[0] + bv[0], zff = zv[1] + bv[1];
        float zg = zv[2] + bv[2], zo = zv[3] + bv[3];
        float ig = sigmoidf_(zi) * fmaxf(zg, 0.f);
        float cv = (MODE == 2) ? (sigmoidf_(zff) * c[p] + ig) : ig;
        if (MODE >= 1) c[p] = cv;
        float h = sigmoidf_(zo) * fmaxf(cv, 0.f);
        hout[(rb * 64 + r) * 512 + cs * 8 + jl] = __float2bfloat16(h);
    }
}

// Per-row-group barrier across the 64 WGs sharing batch rows rb*64..+64.
__device__ __forceinline__ void rb_barrier(unsigned* f, int cs, int tid, unsigned target) {
    __syncthreads();                                  // all stores issued+drained
    if (tid == 0)
        __hip_atomic_store(&f[cs], target, __ATOMIC_RELEASE, __HIP_MEMORY_SCOPE_AGENT);
    if (tid < 64) {
        int lim = 1 << 22;                            // escape hatch: no infinite hang
        while (__hip_atomic_load(&f[tid], __ATOMIC_RELAXED, __HIP_MEMORY_SCOPE_AGENT) < target
               && --lim)
            __builtin_amdgcn_s_sleep(2);
    }
    __syncthreads();
    __threadfence();                                  // acquire: invalidate stale L1/L2
}

// ---- the persistent kernel ------------------------------------------------
// 256 WGs x 256 thr; WG = (rb = wg>>6 in [0,4), cs = wg&63 in [0,64)).
// Owns batch rows rb*64..+64, output cols j in [cs*8, cs*8+8) (32 packed cols).
__global__ __launch_bounds__(256, 1) void lstm_persist(
    const bf16* __restrict__ A0, bf16* __restrict__ h1buf,
    const bf16* __restrict__ We0pk, const bf16* __restrict__ We1pk,
    const bf16* __restrict__ U0, const bf16* __restrict__ U1,
    const float* __restrict__ be0p, const float* __restrict__ be1p,
    const float* __restrict__ b0f, const float* __restrict__ b1f,
    bf16* __restrict__ Hall, unsigned* __restrict__ flags) {
    __shared__ char smem[131072];
    char* u0s = smem;                                 // 32 KB weight slice (parity 0)
    char* u1s = smem + 32768;                         // 32 KB weight slice (parity 1)
    char* at  = smem + 65536;                         // 64 KB A-tile / z overlay
    float* zf = (float*)at;
    const int tid = threadIdx.x, w = tid >> 6, lane = tid & 63;
    const int wg = blockIdx.x, rb = wg >> 6, cs = wg & 63;
    unsigned* f = flags + rb * 64;
    f32x4 acc[2];
    float c[2];

    // ---- encoder layer 0 (K=64) ----
    stage_lds((const char*)(A0 + rb * 64 * 64), at, 64 * 128, 7, tid);
    stage_lds((const char*)(We0pk + cs * 32 * 64), u0s, 32 * 128, 7, tid);
    __syncthreads();
    mfma_cell<64>(at, u0s, w, lane, acc);
    __syncthreads();
    write_z(zf, w, lane, acc);
    __syncthreads();
    gates_store<0>(zf, be0p, rb, cs, tid, c, h1buf);
    rb_barrier(f, cs, tid, 1);

    // ---- encoder layer 1 (K=512): h -> Hall slab 0, c seeded ----
    stage_lds((const char*)(h1buf + rb * 64 * 512), at, 65536, 10, tid);
    stage_lds((const char*)(We1pk + (size_t)cs * 32 * 512), u0s, 32768, 10, tid);
    __syncthreads();
    mfma_cell<512>(at, u0s, w, lane, acc);
    __syncthreads();
    write_z(zf, w, lane, acc);
    __syncthreads();
    gates_store<1>(zf, be1p, rb, cs, tid, c, Hall);
    rb_barrier(f, cs, tid, 2);

    // ---- decoder weights resident in LDS for all 254 cells ----
    stage_lds((const char*)(U0 + (size_t)cs * 32 * 512), u0s, 32768, 10, tid);
    stage_lds((const char*)(U1 + (size_t)cs * 32 * 512), u1s, 32768, 10, tid);

    for (int k = 0; k < 254; ++k) {
        stage_lds((const char*)(Hall + (size_t)k * BH + rb * 64 * 512), at, 65536, 10, tid);
        __syncthreads();
        mfma_cell<512>(at, (k & 1) ? u1s : u0s, w, lane, acc);
        __syncthreads();
        write_z(zf, w, lane, acc);
        __syncthreads();
        gates_store<2>(zf, (k & 1) ? b1f : b0f, rb, cs, tid, c,
                       Hall + (size_t)(k + 1) * BH);
        if (k < 253) rb_barrier(f, cs, tid, 3 + (unsigned)k);
    }
}

// ---- final Y GEMM: (255*256 x 512) @ Wdense(512 x 64) -> out (f32) reversed ----
__global__ void y_kernel(const bf16* __restrict__ Hall, const bf16* __restrict__ Wdpk,
                         const float* __restrict__ bdense, float* __restrict__ out) {
    const int tid = threadIdx.x, w = tid >> 6, lane = tid & 63;
    const int lr = lane & 15, lk = (lane >> 4) * 8;
    const long row0 = (long)blockIdx.x * 64 + w * 16;
    f32x4 acc[4] = {};
    const bf16* Abase = Hall + (row0 + lr) * 512 + lk;
    const bf16* Bbase = Wdpk + lr * 512 + lk;
    #pragma unroll
    for (int kk = 0; kk < 16; ++kk) {
        bf16x8 a = *reinterpret_cast<const bf16x8*>(Abase + kk * 32);
        #pragma unroll
        for (int n = 0; n < 4; ++n) {
            bf16x8 b = *reinterpret_cast<const bf16x8*>(Bbase + n * 16 * 512 + kk * 32);
            acc[n] = __builtin_amdgcn_mfma_f32_16x16x32_bf16(a, b, acc[n], 0, 0, 0);
        }
    }
    #pragma unroll
    for (int n = 0; n < 4; ++n) {
        int dcol = n * 16 + lr;
        float bv = bdense[dcol];
        #pragma unroll
        for (int r = 0; r < 4; ++r) {
            long gr = row0 + (lane >> 4) * 4 + r;
            int s = (int)(gr >> 8), b = (int)(gr & 255);
            out[((long)b * 255 + (254 - s)) * 64 + dcol] = acc[n][r] + bv;
        }
    }
}

extern "C" void kernel_launch(void* const* d_in, const int* in_sizes, int n_in,
                              void* d_out, int out_size, void* d_ws, size_t ws_size,
                              hipStream_t stream) {
    const float* enc    = (const float*)d_in[0];
    const float* We0    = (const float*)d_in[2];
    const float* be0    = (const float*)d_in[4];
    const float* We1    = (const float*)d_in[5];
    const float* be1    = (const float*)d_in[7];
    const float* Wd0    = (const float*)d_in[8];
    const float* Ud0    = (const float*)d_in[9];
    const float* bd0    = (const float*)d_in[10];
    const float* Wd1    = (const float*)d_in[11];
    const float* Ud1    = (const float*)d_in[12];
    const float* bd1    = (const float*)d_in[13];
    const float* Wdense = (const float*)d_in[14];
    const float* bdense = (const float*)d_in[15];
    float* out = (float*)d_out;
    char* ws  = (char*)d_ws;

    bf16*     U0     = (bf16*)(ws + OFF_U0);
    bf16*     U1     = (bf16*)(ws + OFF_U1);
    bf16*     We0pk  = (bf16*)(ws + OFF_WE0PK);
    bf16*     We1pk  = (bf16*)(ws + OFF_WE1PK);
    bf16*     Wdpk   = (bf16*)(ws + OFF_WDPK);
    float*    be0p   = (float*)(ws + OFF_BE0P);
    float*    be1p   = (float*)(ws + OFF_BE1P);
    float*    b0f    = (float*)(ws + OFF_B0F);
    float*    b1f    = (float*)(ws + OFF_B1F);
    bf16*     A0     = (bf16*)(ws + OFF_A0);
    bf16*     h1buf  = (bf16*)(ws + OFF_H1);
    unsigned* flags  = (unsigned*)(ws + OFF_BAR);
    bf16*     Hall   = (bf16*)(ws + OFF_HALL);

    hipMemsetAsync(ws + OFF_BAR, 0, 1024, stream);

    cast_x    <<<64,   256, 0, stream>>>(enc, A0);
    pack_gatew<<<2048, 256, 0, stream>>>(We0, We0pk, 64);
    pack_gatew<<<2048, 256, 0, stream>>>(We1, We1pk, 512);
    pack_wd   <<<64,   256, 0, stream>>>(Wdense, Wdpk);
    fold_u    <<<2048, 256, 0, stream>>>(Wdense, Wd0, Ud0, U0);
    fold_u    <<<2048, 256, 0, stream>>>(Wdense, Wd1, Ud1, U1);
    prep_bias <<<8,    256, 0, stream>>>(be0, be1, bd0, bd1, bdense, Wd0, Wd1,
                                         be0p, be1p, b0f, b1f);

    lstm_persist<<<256, 256, 0, stream>>>(A0, h1buf, We0pk, We1pk, U0, U1,
                                          be0p, be1p, b0f, b1f, Hall, flags);

    y_kernel<<<1020, 256, 0, stream>>>(Hall, Wdpk, bdense, out);
}

// Round 6
// 2025.911 us; speedup vs baseline: 3.3696x; 3.3696x over previous
//
#include <hip/hip_runtime.h>
#include <hip/hip_bf16.h>
#include <cstdint>

typedef __bf16 bf16x8 __attribute__((ext_vector_type(8)));
typedef float  f32x4  __attribute__((ext_vector_type(4)));
typedef __hip_bfloat16 bf16;

__device__ __forceinline__ float sigmoidf_(float x) { return 1.0f / (1.0f + __expf(-x)); }

// Problem: B=256, T=128, D=64, H=512, 4H=2048. Output (256,255,64) f32.
// Packed weight layout: np = j*4 + g  <->  n = g*512 + j.
// ws layout (byte offsets, 16-aligned)
#define OFF_U0      0u           // Ufold0 packed: 2048 x 512 bf16 (2 MB)
#define OFF_U1      2097152u     // Ufold1 packed (2 MB)
#define OFF_WE0PK   4194304u     // We0 packed: 2048 x 64 bf16 (256 KB)
#define OFF_WE1PK   4456448u     // We1 packed: 2048 x 512 bf16 (2 MB)
#define OFF_WDPK    6553600u     // Wdense^T: 64 x 512 bf16 (64 KB)
#define OFF_BE0P    6619136u     // be0 permuted f32 (8 KB)
#define OFF_BE1P    6627328u
#define OFF_B0F     6635520u     // folded dec bias 0 (8 KB)
#define OFF_B1F     6643712u
#define OFF_A0      6651904u     // enc last-step input bf16: 256 x 64 (32 KB)
#define OFF_H1      6684672u     // enc layer1 h bf16: 256 x 512 (256 KB)
#define OFF_BAR     6946816u     // barrier flags: 4 groups x 64 u32 (1 KB)
#define OFF_HALL    7471104u     // h history bf16: 255 x 256 x 512 (66.8 MB)
#define BH          131072       // elems per h slab (256*512)

// ---- one-time prep kernels ----------------------------------------------

__global__ void cast_x(const float* __restrict__ enc, bf16* __restrict__ A0) {
    int i = blockIdx.x * 256 + threadIdx.x;           // 16384 total
    int b = i >> 6, d = i & 63;
    A0[i] = __float2bfloat16(enc[(b * 128 + 127) * 64 + d]);
}

// out[np][k] = W[k][n],  np = j*4+g, n = g*512+j
__global__ void pack_gatew(const float* __restrict__ W, bf16* __restrict__ out, int K) {
    int np = blockIdx.x;
    int j = np >> 2, g = np & 3;
    int n = g * 512 + j;
    for (int k = threadIdx.x; k < K; k += blockDim.x)
        out[np * K + k] = __float2bfloat16(W[k * 2048 + n]);
}

__global__ void pack_wd(const float* __restrict__ Wdense, bf16* __restrict__ out) {
    int d = blockIdx.x;                               // 64
    for (int k = threadIdx.x; k < 512; k += 256)
        out[d * 512 + k] = __float2bfloat16(Wdense[k * 64 + d]);
}

// Ufold[np][hk] = sum_d Wdense[hk][d]*Wd[d][n] + Ud[hk][n]
__global__ void fold_u(const float* __restrict__ Wdense, const float* __restrict__ Wd,
                       const float* __restrict__ Ud, bf16* __restrict__ out) {
    __shared__ float wcol[64];
    int np = blockIdx.x;
    int j = np >> 2, g = np & 3;
    int n = g * 512 + j;
    if (threadIdx.x < 64) wcol[threadIdx.x] = Wd[threadIdx.x * 2048 + n];
    __syncthreads();
    for (int hk = threadIdx.x; hk < 512; hk += 256) {
        float s = Ud[hk * 2048 + n];
        const float* wr = Wdense + hk * 64;
        #pragma unroll
        for (int d = 0; d < 64; ++d) s += wr[d] * wcol[d];
        out[np * 512 + hk] = __float2bfloat16(s);
    }
}

__global__ void prep_bias(const float* __restrict__ be0, const float* __restrict__ be1,
                          const float* __restrict__ bd0, const float* __restrict__ bd1,
                          const float* __restrict__ bdense,
                          const float* __restrict__ Wd0, const float* __restrict__ Wd1,
                          float* __restrict__ be0p, float* __restrict__ be1p,
                          float* __restrict__ b0f, float* __restrict__ b1f) {
    int np = blockIdx.x * blockDim.x + threadIdx.x;
    if (np >= 2048) return;
    int j = np >> 2, g = np & 3;
    int n = g * 512 + j;
    be0p[np] = be0[n];
    be1p[np] = be1[n];
    float s0 = bd0[n], s1 = bd1[n];
    for (int d = 0; d < 64; ++d) {
        float bv = bdense[d];
        s0 += bv * Wd0[d * 2048 + n];
        s1 += bv * Wd1[d * 2048 + n];
    }
    b0f[np] = s0;
    b1f[np] = s1;
}

// ---- persistent-kernel device helpers ------------------------------------

// Plain-cached staging (for weights/A0 produced by earlier dispatches).
__device__ __forceinline__ void stage_lds(const char* __restrict__ g, char* lds,
                                          int nbytes, int rbLog, int tid) {
    for (int off = tid * 16; off < nbytes; off += 256 * 16) {
        uint4 v = *(const uint4*)(g + off);
        int row = off >> rbLog;
        *(uint4*)(lds + (off ^ ((row & 7) << 4))) = v;
    }
}

// Coherent staging of a 64 KB tile (64 rows x 1 KB) via sc0/sc1 loads that
// bypass L1/L2 (read from L3 coherence point). 2 rounds x 8 x 16B per thread.
__device__ __forceinline__ void stage_coh64k(const char* __restrict__ g, char* lds,
                                             int tid) {
    #pragma unroll
    for (int i = 0; i < 2; ++i) {
        int off = i * 32768 + tid * 128;
        const char* p = g + off;
        uint4 v0, v1, v2, v3, v4, v5, v6, v7;
        asm volatile(
            "global_load_dwordx4 %0, %8, off sc0 sc1\n\t"
            "global_load_dwordx4 %1, %8, off offset:16 sc0 sc1\n\t"
            "global_load_dwordx4 %2, %8, off offset:32 sc0 sc1\n\t"
            "global_load_dwordx4 %3, %8, off offset:48 sc0 sc1\n\t"
            "global_load_dwordx4 %4, %8, off offset:64 sc0 sc1\n\t"
            "global_load_dwordx4 %5, %8, off offset:80 sc0 sc1\n\t"
            "global_load_dwordx4 %6, %8, off offset:96 sc0 sc1\n\t"
            "global_load_dwordx4 %7, %8, off offset:112 sc0 sc1\n\t"
            "s_waitcnt vmcnt(0)"
            : "=v"(v0), "=v"(v1), "=v"(v2), "=v"(v3),
              "=v"(v4), "=v"(v5), "=v"(v6), "=v"(v7)
            : "v"(p) : "memory");
        int row = off >> 10;
        int sw = (row & 7) << 4;
        *(uint4*)(lds + ((off +   0) ^ sw)) = v0;
        *(uint4*)(lds + ((off +  16) ^ sw)) = v1;
        *(uint4*)(lds + ((off +  32) ^ sw)) = v2;
        *(uint4*)(lds + ((off +  48) ^ sw)) = v3;
        *(uint4*)(lds + ((off +  64) ^ sw)) = v4;
        *(uint4*)(lds + ((off +  80) ^ sw)) = v5;
        *(uint4*)(lds + ((off +  96) ^ sw)) = v6;
        *(uint4*)(lds + ((off + 112) ^ sw)) = v7;
    }
}

__device__ __forceinline__ void store_coh32(unsigned* p, unsigned v) {
    asm volatile("global_store_dword %0, %1, off sc0 sc1"
                 :: "v"(p), "v"(v) : "memory");
}

// Wave-tile 16 rows x 32 pcols, K=KDIM.
template <int KDIM>
__device__ __forceinline__ void mfma_cell(const char* at, const char* ut,
                                          int w, int lane, f32x4 acc[2]) {
    const int lr = lane & 15, kq = lane >> 4;
    constexpr int RB = KDIM * 2;
    acc[0] = f32x4{0.f, 0.f, 0.f, 0.f};
    acc[1] = f32x4{0.f, 0.f, 0.f, 0.f};
    #pragma unroll
    for (int kk = 0; kk < KDIM / 32; ++kk) {
        int colb = kk * 64 + kq * 16;
        int arow = w * 16 + lr;
        bf16x8 a = *(const bf16x8*)(at + arow * RB + (colb ^ ((arow & 7) << 4)));
        #pragma unroll
        for (int n = 0; n < 2; ++n) {
            int brow = n * 16 + lr;
            bf16x8 b = *(const bf16x8*)(ut + brow * RB + (colb ^ ((brow & 7) << 4)));
            acc[n] = __builtin_amdgcn_mfma_f32_16x16x32_bf16(a, b, acc[n], 0, 0, 0);
        }
    }
}

// D layout: col = lane&15, row = (lane>>4)*4 + r  [verified m89/m91, r4/r5-passing]
__device__ __forceinline__ void write_z(float* zf, int w, int lane, const f32x4 acc[2]) {
    #pragma unroll
    for (int n = 0; n < 2; ++n)
        #pragma unroll
        for (int r = 0; r < 4; ++r)
            zf[(w * 16 + (lane >> 4) * 4 + r) * 36 + n * 16 + (lane & 15)] = acc[n][r];
}

// MODE: 0 = enc no-c, 1 = enc init-c, 2 = dec (uses+updates c)
// Thread (r = tid>>2, q = tid&3) owns row r, cols {2q, 2q+1}; packs 2 bf16 -> 1 u32
// coherent store (write-through to L3, no L2 allocation anywhere).
template <int MODE>
__device__ __forceinline__ void gates_store(const float* zf, const float* __restrict__ bias,
                                            int rb, int cs, int tid, float c[2],
                                            bf16* __restrict__ hout) {
    int r = tid >> 2, q = tid & 3;
    unsigned out2 = 0;
    #pragma unroll
    for (int p = 0; p < 2; ++p) {
        f32x4 zv = *(const f32x4*)(zf + r * 36 + q * 8 + p * 4);
        f32x4 bv = *(const f32x4*)(bias + (cs * 8 + q * 2 + p) * 4);
        float zi = zv[0] + bv[0], zff = zv[1] + bv[1];
        float zg = zv[2] + bv[2], zo = zv[3] + bv[3];
        float ig = sigmoidf_(zi) * fmaxf(zg, 0.f);
        float cv = (MODE == 2) ? (sigmoidf_(zff) * c[p] + ig) : ig;
        if (MODE >= 1) c[p] = cv;
        float h = sigmoidf_(zo) * fmaxf(cv, 0.f);
        unsigned short us = __builtin_bit_cast(unsigned short, __float2bfloat16(h));
        out2 |= (unsigned)us << (16 * p);
    }
    store_coh32((unsigned*)((char*)hout +
                (size_t)((rb * 64 + r) * 512 + cs * 8 + q * 2) * 2), out2);
}

// Per-row-group barrier across the 64 WGs sharing batch rows rb*64..+64.
// No wbl2/inv: data+flags all travel via sc0/sc1 (L3 coherence point).
__device__ __forceinline__ void rb_barrier(unsigned* f, int cs, int tid, unsigned target) {
    asm volatile("s_waitcnt vmcnt(0)" ::: "memory");  // this wave's h stores at L3
    __syncthreads();                                  // all waves drained
    if (tid == 0)
        asm volatile("global_store_dword %0, %1, off sc0 sc1\n\t"
                     "s_waitcnt vmcnt(0)"
                     :: "v"(&f[cs]), "v"(target) : "memory");
    if (tid < 64) {
        unsigned v = 0;
        int lim = 1 << 20;                            // escape hatch: no infinite hang
        do {
            asm volatile("global_load_dword %0, %1, off sc0 sc1\n\t"
                         "s_waitcnt vmcnt(0)"
                         : "=v"(v) : "v"(&f[tid]) : "memory");
        } while (v < target && --lim);
    }
    __syncthreads();
}

// ---- the persistent kernel ------------------------------------------------
// 256 WGs x 256 thr; WG = (rb = wg>>6 in [0,4), cs = wg&63 in [0,64)).
__global__ __launch_bounds__(256, 1) void lstm_persist(
    const bf16* __restrict__ A0, bf16* __restrict__ h1buf,
    const bf16* __restrict__ We0pk, const bf16* __restrict__ We1pk,
    const bf16* __restrict__ U0, const bf16* __restrict__ U1,
    const float* __restrict__ be0p, const float* __restrict__ be1p,
    const float* __restrict__ b0f, const float* __restrict__ b1f,
    bf16* __restrict__ Hall, unsigned* __restrict__ flags) {
    __shared__ char smem[131072];
    char* u0s = smem;                                 // 32 KB weight slice (parity 0)
    char* u1s = smem + 32768;                         // 32 KB weight slice (parity 1)
    char* at  = smem + 65536;                         // 64 KB A-tile / z overlay
    float* zf = (float*)at;
    const int tid = threadIdx.x, w = tid >> 6, lane = tid & 63;
    const int wg = blockIdx.x, rb = wg >> 6, cs = wg & 63;
    unsigned* f = flags + rb * 64;
    f32x4 acc[2];
    float c[2];

    // ---- encoder layer 0 (K=64); A0/We0pk are prior-dispatch products ----
    stage_lds((const char*)(A0 + rb * 64 * 64), at, 8192, 7, tid);
    stage_lds((const char*)(We0pk + cs * 32 * 64), u0s, 4096, 7, tid);
    __syncthreads();
    mfma_cell<64>(at, u0s, w, lane, acc);
    __syncthreads();
    write_z(zf, w, lane, acc);
    __syncthreads();
    gates_store<0>(zf, be0p, rb, cs, tid, c, h1buf);
    rb_barrier(f, cs, tid, 1);

    // ---- encoder layer 1 (K=512): h -> Hall slab 0, c seeded ----
    stage_coh64k((const char*)(h1buf + rb * 64 * 512), at, tid);
    stage_lds((const char*)(We1pk + (size_t)cs * 32 * 512), u0s, 32768, 10, tid);
    __syncthreads();
    mfma_cell<512>(at, u0s, w, lane, acc);
    __syncthreads();
    write_z(zf, w, lane, acc);
    __syncthreads();
    gates_store<1>(zf, be1p, rb, cs, tid, c, Hall);
    rb_barrier(f, cs, tid, 2);

    // ---- decoder weights resident in LDS for all 254 cells ----
    stage_lds((const char*)(U0 + (size_t)cs * 32 * 512), u0s, 32768, 10, tid);
    stage_lds((const char*)(U1 + (size_t)cs * 32 * 512), u1s, 32768, 10, tid);

    for (int k = 0; k < 254; ++k) {
        stage_coh64k((const char*)(Hall + (size_t)k * BH + rb * 64 * 512), at, tid);
        __syncthreads();
        mfma_cell<512>(at, (k & 1) ? u1s : u0s, w, lane, acc);
        __syncthreads();
        write_z(zf, w, lane, acc);
        __syncthreads();
        gates_store<2>(zf, (k & 1) ? b1f : b0f, rb, cs, tid, c,
                       Hall + (size_t)(k + 1) * BH);
        if (k < 253) rb_barrier(f, cs, tid, 3 + (unsigned)k);
    }
}

// ---- final Y GEMM: (255*256 x 512) @ Wdense(512 x 64) -> out (f32) reversed ----
__global__ void y_kernel(const bf16* __restrict__ Hall, const bf16* __restrict__ Wdpk,
                         const float* __restrict__ bdense, float* __restrict__ out) {
    const int tid = threadIdx.x, w = tid >> 6, lane = tid & 63;
    const int lr = lane & 15, lk = (lane >> 4) * 8;
    const long row0 = (long)blockIdx.x * 64 + w * 16;
    f32x4 acc[4] = {};
    const bf16* Abase = Hall + (row0 + lr) * 512 + lk;
    const bf16* Bbase = Wdpk + lr * 512 + lk;
    #pragma unroll
    for (int kk = 0; kk < 16; ++kk) {
        bf16x8 a = *reinterpret_cast<const bf16x8*>(Abase + kk * 32);
        #pragma unroll
        for (int n = 0; n < 4; ++n) {
            bf16x8 b = *reinterpret_cast<const bf16x8*>(Bbase + n * 16 * 512 + kk * 32);
            acc[n] = __builtin_amdgcn_mfma_f32_16x16x32_bf16(a, b, acc[n], 0, 0, 0);
        }
    }
    #pragma unroll
    for (int n = 0; n < 4; ++n) {
        int dcol = n * 16 + lr;
        float bv = bdense[dcol];
        #pragma unroll
        for (int r = 0; r < 4; ++r) {
            long gr = row0 + (lane >> 4) * 4 + r;
            int s = (int)(gr >> 8), b = (int)(gr & 255);
            out[((long)b * 255 + (254 - s)) * 64 + dcol] = acc[n][r] + bv;
        }
    }
}

extern "C" void kernel_launch(void* const* d_in, const int* in_sizes, int n_in,
                              void* d_out, int out_size, void* d_ws, size_t ws_size,
                              hipStream_t stream) {
    const float* enc    = (const float*)d_in[0];
    const float* We0    = (const float*)d_in[2];
    const float* be0    = (const float*)d_in[4];
    const float* We1    = (const float*)d_in[5];
    const float* be1    = (const float*)d_in[7];
    const float* Wd0    = (const float*)d_in[8];
    const float* Ud0    = (const float*)d_in[9];
    const float* bd0    = (const float*)d_in[10];
    const float* Wd1    = (const float*)d_in[11];
    const float* Ud1    = (const float*)d_in[12];
    const float* bd1    = (const float*)d_in[13];
    const float* Wdense = (const float*)d_in[14];
    const float* bdense = (const float*)d_in[15];
    float* out = (float*)d_out;
    char* ws  = (char*)d_ws;

    bf16*     U0     = (bf16*)(ws + OFF_U0);
    bf16*     U1     = (bf16*)(ws + OFF_U1);
    bf16*     We0pk  = (bf16*)(ws + OFF_WE0PK);
    bf16*     We1pk  = (bf16*)(ws + OFF_WE1PK);
    bf16*     Wdpk   = (bf16*)(ws + OFF_WDPK);
    float*    be0p   = (float*)(ws + OFF_BE0P);
    float*    be1p   = (float*)(ws + OFF_BE1P);
    float*    b0f    = (float*)(ws + OFF_B0F);
    float*    b1f    = (float*)(ws + OFF_B1F);
    bf16*     A0     = (bf16*)(ws + OFF_A0);
    bf16*     h1buf  = (bf16*)(ws + OFF_H1);
    unsigned* flags  = (unsigned*)(ws + OFF_BAR);
    bf16*     Hall   = (bf16*)(ws + OFF_HALL);

    hipMemsetAsync(ws + OFF_BAR, 0, 1024, stream);

    cast_x    <<<64,   256, 0, stream>>>(enc, A0);
    pack_gatew<<<2048, 256, 0, stream>>>(We0, We0pk, 64);
    pack_gatew<<<2048, 256, 0, stream>>>(We1, We1pk, 512);
    pack_wd   <<<64,   256, 0, stream>>>(Wdense, Wdpk);
    fold_u    <<<2048, 256, 0, stream>>>(Wdense, Wd0, Ud0, U0);
    fold_u    <<<2048, 256, 0, stream>>>(Wdense, Wd1, Ud1, U1);
    prep_bias <<<8,    256, 0, stream>>>(be0, be1, bd0, bd1, bdense, Wd0, Wd1,
                                         be0p, be1p, b0f, b1f);

    lstm_persist<<<256, 256, 0, stream>>>(A0, h1buf, We0pk, We1pk, U0, U1,
                                          be0p, be1p, b0f, b1f, Hall, flags);

    y_kernel<<<1020, 256, 0, stream>>>(Hall, Wdpk, bdense, out);
}

// Round 9
// 1956.666 us; speedup vs baseline: 3.4889x; 1.0354x over previous
//
#include <hip/hip_runtime.h>
#include <hip/hip_bf16.h>
#include <cstdint>

typedef __bf16 bf16x8 __attribute__((ext_vector_type(8)));
typedef float  f32x4  __attribute__((ext_vector_type(4)));
typedef __hip_bfloat16 bf16;

__device__ __forceinline__ float sigmoidf_(float x) { return 1.0f / (1.0f + __expf(-x)); }

// Problem: B=256, T=128, D=64, H=512, 4H=2048. Output (256,255,64) f32.
// Packed weight layout: np = j*4 + g  <->  n = g*512 + j.
// ws layout (byte offsets, 16-aligned)
#define OFF_U0      0u           // Ufold0 packed: 2048 x 512 bf16 (2 MB)
#define OFF_U1      2097152u     // Ufold1 packed (2 MB)
#define OFF_WE0PK   4194304u     // We0 packed: 2048 x 64 bf16 (256 KB)
#define OFF_WE1PK   4456448u     // We1 packed: 2048 x 512 bf16 (2 MB)
#define OFF_WDPK    6553600u     // Wdense^T: 64 x 512 bf16 (64 KB)
#define OFF_BE0P    6619136u     // be0 permuted f32 (8 KB)
#define OFF_BE1P    6627328u
#define OFF_B0F     6635520u     // folded dec bias 0 (8 KB)
#define OFF_B1F     6643712u
#define OFF_A0      6651904u     // enc last-step input bf16: 256 x 64 (32 KB)
#define OFF_H1      6684672u     // enc layer1 h bf16: 256 x 512 (256 KB)
#define OFF_BAR     6946816u     // barrier flags: 4 groups x 64 u32 (1 KB)
#define OFF_HALL    7471104u     // h history bf16: 255 x 256 x 512 (66.8 MB)
#define BH          131072       // elems per h slab (256*512)

// ---- one-time prep kernels ----------------------------------------------

__global__ void cast_x(const float* __restrict__ enc, bf16* __restrict__ A0) {
    int i = blockIdx.x * 256 + threadIdx.x;           // 16384 total
    int b = i >> 6, d = i & 63;
    A0[i] = __float2bfloat16(enc[(b * 128 + 127) * 64 + d]);
}

// out[np][k] = W[k][n],  np = j*4+g, n = g*512+j
__global__ void pack_gatew(const float* __restrict__ W, bf16* __restrict__ out, int K) {
    int np = blockIdx.x;
    int j = np >> 2, g = np & 3;
    int n = g * 512 + j;
    for (int k = threadIdx.x; k < K; k += blockDim.x)
        out[np * K + k] = __float2bfloat16(W[k * 2048 + n]);
}

__global__ void pack_wd(const float* __restrict__ Wdense, bf16* __restrict__ out) {
    int d = blockIdx.x;                               // 64
    for (int k = threadIdx.x; k < 512; k += 256)
        out[d * 512 + k] = __float2bfloat16(Wdense[k * 64 + d]);
}

// Ufold[np][hk] = sum_d Wdense[hk][d]*Wd[d][n] + Ud[hk][n]
__global__ void fold_u(const float* __restrict__ Wdense, const float* __restrict__ Wd,
                       const float* __restrict__ Ud, bf16* __restrict__ out) {
    __shared__ float wcol[64];
    int np = blockIdx.x;
    int j = np >> 2, g = np & 3;
    int n = g * 512 + j;
    if (threadIdx.x < 64) wcol[threadIdx.x] = Wd[threadIdx.x * 2048 + n];
    __syncthreads();
    for (int hk = threadIdx.x; hk < 512; hk += 256) {
        float s = Ud[hk * 2048 + n];
        const float* wr = Wdense + hk * 64;
        #pragma unroll
        for (int d = 0; d < 64; ++d) s += wr[d] * wcol[d];
        out[np * 512 + hk] = __float2bfloat16(s);
    }
}

__global__ void prep_bias(const float* __restrict__ be0, const float* __restrict__ be1,
                          const float* __restrict__ bd0, const float* __restrict__ bd1,
                          const float* __restrict__ bdense,
                          const float* __restrict__ Wd0, const float* __restrict__ Wd1,
                          float* __restrict__ be0p, float* __restrict__ be1p,
                          float* __restrict__ b0f, float* __restrict__ b1f,
                          unsigned* __restrict__ flags) {
    int np = blockIdx.x * blockDim.x + threadIdx.x;
    if (np < 256) {                                   // zero flags at coherence point
        unsigned z = 0;
        asm volatile("global_store_dword %0, %1, off sc0 sc1"
                     :: "v"(&flags[np]), "v"(z) : "memory");
    }
    if (np >= 2048) return;
    int j = np >> 2, g = np & 3;
    int n = g * 512 + j;
    be0p[np] = be0[n];
    be1p[np] = be1[n];
    float s0 = bd0[n], s1 = bd1[n];
    for (int d = 0; d < 64; ++d) {
        float bv = bdense[d];
        s0 += bv * Wd0[d * 2048 + n];
        s1 += bv * Wd1[d * 2048 + n];
    }
    b0f[np] = s0;
    b1f[np] = s1;
}

// ---- persistent-kernel device helpers ------------------------------------

// Plain-cached staging (for weights/A0 produced by earlier dispatches).
__device__ __forceinline__ void stage_lds(const char* __restrict__ g, char* lds,
                                          int nbytes, int rbLog, int tid) {
    for (int off = tid * 16; off < nbytes; off += 256 * 16) {
        uint4 v = *(const uint4*)(g + off);
        int row = off >> rbLog;
        *(uint4*)(lds + (off ^ ((row & 7) << 4))) = v;
    }
}

// Coherent staging of a 64 KB tile (64 rows x 1 KB) via sc0/sc1 loads that
// bypass to the coherence point. Per-block internal drain (R6-known-good).
// "=&v" early-clobber: outputs must NOT alias the address pair (async-load
// register-overlap fault otherwise — R8 post-mortem).
__device__ __forceinline__ void stage_coh64k(const char* __restrict__ g, char* lds,
                                             int tid) {
    #pragma unroll
    for (int i = 0; i < 2; ++i) {
        int off = i * 32768 + tid * 128;
        const char* p = g + off;
        uint4 v0, v1, v2, v3, v4, v5, v6, v7;
        asm volatile(
            "global_load_dwordx4 %0, %8, off sc0 sc1\n\t"
            "global_load_dwordx4 %1, %8, off offset:16 sc0 sc1\n\t"
            "global_load_dwordx4 %2, %8, off offset:32 sc0 sc1\n\t"
            "global_load_dwordx4 %3, %8, off offset:48 sc0 sc1\n\t"
            "global_load_dwordx4 %4, %8, off offset:64 sc0 sc1\n\t"
            "global_load_dwordx4 %5, %8, off offset:80 sc0 sc1\n\t"
            "global_load_dwordx4 %6, %8, off offset:96 sc0 sc1\n\t"
            "global_load_dwordx4 %7, %8, off offset:112 sc0 sc1\n\t"
            "s_waitcnt vmcnt(0)"
            : "=&v"(v0), "=&v"(v1), "=&v"(v2), "=&v"(v3),
              "=&v"(v4), "=&v"(v5), "=&v"(v6), "=&v"(v7)
            : "v"(p) : "memory");
        int row = off >> 10;
        int sw = (row & 7) << 4;
        *(uint4*)(lds + ((off +   0) ^ sw)) = v0;
        *(uint4*)(lds + ((off +  16) ^ sw)) = v1;
        *(uint4*)(lds + ((off +  32) ^ sw)) = v2;
        *(uint4*)(lds + ((off +  48) ^ sw)) = v3;
        *(uint4*)(lds + ((off +  64) ^ sw)) = v4;
        *(uint4*)(lds + ((off +  80) ^ sw)) = v5;
        *(uint4*)(lds + ((off +  96) ^ sw)) = v6;
        *(uint4*)(lds + ((off + 112) ^ sw)) = v7;
    }
}

__device__ __forceinline__ void store_coh32(unsigned* p, unsigned v) {
    asm volatile("global_store_dword %0, %1, off sc0 sc1"
                 :: "v"(p), "v"(v) : "memory");
}

// Wave-tile 16 rows x 32 pcols, K=KDIM.
template <int KDIM>
__device__ __forceinline__ void mfma_cell(const char* at, const char* ut,
                                          int w, int lane, f32x4 acc[2]) {
    const int lr = lane & 15, kq = lane >> 4;
    constexpr int RB = KDIM * 2;
    acc[0] = f32x4{0.f, 0.f, 0.f, 0.f};
    acc[1] = f32x4{0.f, 0.f, 0.f, 0.f};
    #pragma unroll
    for (int kk = 0; kk < KDIM / 32; ++kk) {
        int colb = kk * 64 + kq * 16;
        int arow = w * 16 + lr;
        bf16x8 a = *(const bf16x8*)(at + arow * RB + (colb ^ ((arow & 7) << 4)));
        #pragma unroll
        for (int n = 0; n < 2; ++n) {
            int brow = n * 16 + lr;
            bf16x8 b = *(const bf16x8*)(ut + brow * RB + (colb ^ ((brow & 7) << 4)));
            acc[n] = __builtin_amdgcn_mfma_f32_16x16x32_bf16(a, b, acc[n], 0, 0, 0);
        }
    }
}

// D layout: col = lane&15, row = (lane>>4)*4 + r  [verified m89/m91, r4-r6 passing]
__device__ __forceinline__ void write_z(float* zf, int w, int lane, const f32x4 acc[2]) {
    #pragma unroll
    for (int n = 0; n < 2; ++n)
        #pragma unroll
        for (int r = 0; r < 4; ++r)
            zf[(w * 16 + (lane >> 4) * 4 + r) * 36 + n * 16 + (lane & 15)] = acc[n][r];
}

// MODE: 0 = enc no-c, 1 = enc init-c, 2 = dec (uses+updates c).
// Thread (r=tid>>2, q=tid&3) owns row r, cols {2q,2q+1}. Reads ONLY own-wave zf
// rows (r in [w*16,w*16+16) for tid in wave w) -> no sync needed after write_z.
// Bias passed in registers (bva = col 2q, bvb = col 2q+1).
template <int MODE>
__device__ __forceinline__ void gates_core(const float* zf, f32x4 bva, f32x4 bvb,
                                           int rb, int cs, int tid, float c[2],
                                           bf16* __restrict__ hout) {
    int r = tid >> 2, q = tid & 3;
    unsigned out2 = 0;
    #pragma unroll
    for (int p = 0; p < 2; ++p) {
        f32x4 zv = *(const f32x4*)(zf + r * 36 + q * 8 + p * 4);
        f32x4 bv = (p == 0) ? bva : bvb;
        float zi = zv[0] + bv[0], zff = zv[1] + bv[1];
        float zg = zv[2] + bv[2], zo = zv[3] + bv[3];
        float ig = sigmoidf_(zi) * fmaxf(zg, 0.f);
        float cv = (MODE == 2) ? (sigmoidf_(zff) * c[p] + ig) : ig;
        if (MODE >= 1) c[p] = cv;
        float h = sigmoidf_(zo) * fmaxf(cv, 0.f);
        unsigned short us = __builtin_bit_cast(unsigned short, __float2bfloat16(h));
        out2 |= (unsigned)us << (16 * p);
    }
    store_coh32((unsigned*)((char*)hout +
                (size_t)((rb * 64 + r) * 512 + cs * 8 + q * 2) * 2), out2);
}

// Per-row-group barrier across the 64 WGs sharing batch rows rb*64..+64.
// All data+flags travel via sc0/sc1 (coherence point); no wbl2/inv needed.
__device__ __forceinline__ void rb_barrier(unsigned* f, int cs, int tid, unsigned target) {
    asm volatile("s_waitcnt vmcnt(0)" ::: "memory");  // this wave's h stores visible
    __syncthreads();                                  // all waves drained
    if (tid == 0) {
        unsigned t = target;
        asm volatile("global_store_dword %0, %1, off sc0 sc1\n\t"
                     "s_waitcnt vmcnt(0)"
                     :: "v"(&f[cs]), "v"(t) : "memory");
    }
    if (tid < 64) {
        unsigned v = 0;
        int lim = 1 << 20;                            // escape hatch: no infinite hang
        for (;;) {
            asm volatile("global_load_dword %0, %1, off sc0 sc1\n\t"
                         "s_waitcnt vmcnt(0)"
                         : "=&v"(v) : "v"(&f[tid]) : "memory");
            if (v >= target || !--lim) break;
            __builtin_amdgcn_s_sleep(1);              // backoff: cut poll pressure
        }
    }
    __syncthreads();
}

// ---- the persistent kernel ------------------------------------------------
// 256 WGs x 256 thr; WG = (rb = wg>>6 in [0,4), cs = wg&63 in [0,64)).
__global__ __launch_bounds__(256, 1) void lstm_persist(
    const bf16* __restrict__ A0, bf16* __restrict__ h1buf,
    const bf16* __restrict__ We0pk, const bf16* __restrict__ We1pk,
    const bf16* __restrict__ U0, const bf16* __restrict__ U1,
    const float* __restrict__ be0p, const float* __restrict__ be1p,
    const float* __restrict__ b0f, const float* __restrict__ b1f,
    bf16* __restrict__ Hall, unsigned* __restrict__ flags) {
    __shared__ char smem[140288];
    char* u0s = smem;                                 // 32 KB weight slice (parity 0)
    char* u1s = smem + 32768;                         // 32 KB weight slice (parity 1)
    char* at  = smem + 65536;                         // 64 KB A-tile
    float* zf = (float*)(smem + 131072);              // 9 KB z (separate region)
    const int tid = threadIdx.x, w = tid >> 6, lane = tid & 63;
    const int wg = blockIdx.x, rb = wg >> 6, cs = wg & 63;
    unsigned* f = flags + rb * 64;
    f32x4 acc[2];
    float c[2];
    const int q = tid & 3;

    // ---- encoder layer 0 (K=64); A0/We0pk are prior-dispatch products ----
    stage_lds((const char*)(A0 + rb * 64 * 64), at, 8192, 7, tid);
    stage_lds((const char*)(We0pk + cs * 32 * 64), u0s, 4096, 7, tid);
    __syncthreads();
    mfma_cell<64>(at, u0s, w, lane, acc);
    write_z(zf, w, lane, acc);
    {
        const float* bp = be0p + (cs * 8 + q * 2) * 4;
        gates_core<0>(zf, *(const f32x4*)bp, *(const f32x4*)(bp + 4),
                      rb, cs, tid, c, h1buf);
    }
    rb_barrier(f, cs, tid, 1);

    // ---- encoder layer 1 (K=512): h -> Hall slab 0, c seeded ----
    stage_coh64k((const char*)(h1buf + rb * 64 * 512), at, tid);
    stage_lds((const char*)(We1pk + (size_t)cs * 32 * 512), u0s, 32768, 10, tid);
    __syncthreads();
    mfma_cell<512>(at, u0s, w, lane, acc);
    write_z(zf, w, lane, acc);
    {
        const float* bp = be1p + (cs * 8 + q * 2) * 4;
        gates_core<1>(zf, *(const f32x4*)bp, *(const f32x4*)(bp + 4),
                      rb, cs, tid, c, Hall);
    }
    rb_barrier(f, cs, tid, 2);

    // ---- decoder weights resident in LDS for all 254 cells ----
    stage_lds((const char*)(U0 + (size_t)cs * 32 * 512), u0s, 32768, 10, tid);
    stage_lds((const char*)(U1 + (size_t)cs * 32 * 512), u1s, 32768, 10, tid);
    // (first loop iteration's __syncthreads covers these stages)

    // folded decoder biases preloaded to registers (both parities)
    const float* bp0 = b0f + (cs * 8 + q * 2) * 4;
    const float* bp1 = b1f + (cs * 8 + q * 2) * 4;
    f32x4 b0a = *(const f32x4*)bp0, b0b = *(const f32x4*)(bp0 + 4);
    f32x4 b1a = *(const f32x4*)bp1, b1b = *(const f32x4*)(bp1 + 4);

    for (int k = 0; k < 254; ++k) {
        stage_coh64k((const char*)(Hall + (size_t)k * BH + rb * 64 * 512), at, tid);
        __syncthreads();
        mfma_cell<512>(at, (k & 1) ? u1s : u0s, w, lane, acc);
        write_z(zf, w, lane, acc);
        gates_core<2>(zf, (k & 1) ? b1a : b0a, (k & 1) ? b1b : b0b,
                      rb, cs, tid, c, Hall + (size_t)(k + 1) * BH);
        if (k < 253) rb_barrier(f, cs, tid, 3 + (unsigned)k);
    }
}

// ---- final Y GEMM: (255*256 x 512) @ Wdense(512 x 64) -> out (f32) reversed ----
__global__ void y_kernel(const bf16* __restrict__ Hall, const bf16* __restrict__ Wdpk,
                         const float* __restrict__ bdense, float* __restrict__ out) {
    const int tid = threadIdx.x, w = tid >> 6, lane = tid & 63;
    const int lr = lane & 15, lk = (lane >> 4) * 8;
    const long row0 = (long)blockIdx.x * 64 + w * 16;
    f32x4 acc[4] = {};
    const bf16* Abase = Hall + (row0 + lr) * 512 + lk;
    const bf16* Bbase = Wdpk + lr * 512 + lk;
    #pragma unroll
    for (int kk = 0; kk < 16; ++kk) {
        bf16x8 a = *reinterpret_cast<const bf16x8*>(Abase + kk * 32);
        #pragma unroll
        for (int n = 0; n < 4; ++n) {
            bf16x8 b = *reinterpret_cast<const bf16x8*>(Bbase + n * 16 * 512 + kk * 32);
            acc[n] = __builtin_amdgcn_mfma_f32_16x16x32_bf16(a, b, acc[n], 0, 0, 0);
        }
    }
    #pragma unroll
    for (int n = 0; n < 4; ++n) {
        int dcol = n * 16 + lr;
        float bv = bdense[dcol];
        #pragma unroll
        for (int r = 0; r < 4; ++r) {
            long gr = row0 + (lane >> 4) * 4 + r;
            int s = (int)(gr >> 8), b = (int)(gr & 255);
            out[((long)b * 255 + (254 - s)) * 64 + dcol] = acc[n][r] + bv;
        }
    }
}

extern "C" void kernel_launch(void* const* d_in, const int* in_sizes, int n_in,
                              void* d_out, int out_size, void* d_ws, size_t ws_size,
                              hipStream_t stream) {
    const float* enc    = (const float*)d_in[0];
    const float* We0    = (const float*)d_in[2];
    const float* be0    = (const float*)d_in[4];
    const float* We1    = (const float*)d_in[5];
    const float* be1    = (const float*)d_in[7];
    const float* Wd0    = (const float*)d_in[8];
    const float* Ud0    = (const float*)d_in[9];
    const float* bd0    = (const float*)d_in[10];
    const float* Wd1    = (const float*)d_in[11];
    const float* Ud1    = (const float*)d_in[12];
    const float* bd1    = (const float*)d_in[13];
    const float* Wdense = (const float*)d_in[14];
    const float* bdense = (const float*)d_in[15];
    float* out = (float*)d_out;
    char* ws  = (char*)d_ws;

    bf16*     U0     = (bf16*)(ws + OFF_U0);
    bf16*     U1     = (bf16*)(ws + OFF_U1);
    bf16*     We0pk  = (bf16*)(ws + OFF_WE0PK);
    bf16*     We1pk  = (bf16*)(ws + OFF_WE1PK);
    bf16*     Wdpk   = (bf16*)(ws + OFF_WDPK);
    float*    be0p   = (float*)(ws + OFF_BE0P);
    float*    be1p   = (float*)(ws + OFF_BE1P);
    float*    b0f    = (float*)(ws + OFF_B0F);
    float*    b1f    = (float*)(ws + OFF_B1F);
    bf16*     A0     = (bf16*)(ws + OFF_A0);
    bf16*     h1buf  = (bf16*)(ws + OFF_H1);
    unsigned* flags  = (unsigned*)(ws + OFF_BAR);
    bf16*     Hall   = (bf16*)(ws + OFF_HALL);

    hipMemsetAsync(ws + OFF_BAR, 0, 1024, stream);

    cast_x    <<<64,   256, 0, stream>>>(enc, A0);
    pack_gatew<<<2048, 256, 0, stream>>>(We0, We0pk, 64);
    pack_gatew<<<2048, 256, 0, stream>>>(We1, We1pk, 512);
    pack_wd   <<<64,   256, 0, stream>>>(Wdense, Wdpk);
    fold_u    <<<2048, 256, 0, stream>>>(Wdense, Wd0, Ud0, U0);
    fold_u    <<<2048, 256, 0, stream>>>(Wdense, Wd1, Ud1, U1);
    prep_bias <<<8,    256, 0, stream>>>(be0, be1, bd0, bd1, bdense, Wd0, Wd1,
                                         be0p, be1p, b0f, b1f, flags);

    lstm_persist<<<256, 256, 0, stream>>>(A0, h1buf, We0pk, We1pk, U0, U1,
                                          be0p, be1p, b0f, b1f, Hall, flags);

    y_kernel<<<1020, 256, 0, stream>>>(Hall, Wdpk, bdense, out);
}